// Round 10
// baseline (444.703 us; speedup 1.0000x reference)
//
#include <hip/hip_runtime.h>
#include <hip/hip_bf16.h>
#include <stdint.h>

#define B_ 8
#define T_ 2048
#define C_ 384
#define H_ 6
#define D_ 64
#define M_ (B_*T_)   // 16384

typedef unsigned short u16;
typedef unsigned int u32;
typedef __attribute__((ext_vector_type(8))) short short8;
typedef __attribute__((ext_vector_type(4))) float floatx4;

__device__ __forceinline__ float b2f(u16 v) {
  union { unsigned u; float f; } x; x.u = ((unsigned)v) << 16; return x.f;
}
__device__ __forceinline__ u16 f2b(float f) {
  union { float f; unsigned u; } x; x.f = f;
  unsigned r = x.u + 0x7fffu + ((x.u >> 16) & 1u);  // round-nearest-even
  return (u16)(r >> 16);
}
__device__ __forceinline__ u32 pack_bf16(float a, float b) {
  union { __hip_bfloat162 h; u32 u; } x;
  x.h = __float22bfloat162_rn(float2{a, b});
  return x.u;
}
__device__ __forceinline__ uint4 pack8(const float4& lo, const float4& hi) {
  uint4 r;
  r.x = pack_bf16(lo.x, lo.y); r.y = pack_bf16(lo.z, lo.w);
  r.z = pack_bf16(hi.x, hi.y); r.w = pack_bf16(hi.z, hi.w);
  return r;
}

// ---------------------------------------------------------------------------
// Weights fp32 -> bf16, all four in one launch (grid.y = which weight)
// ---------------------------------------------------------------------------
__global__ __launch_bounds__(256) void cvt_w4(
    const float* __restrict__ s0, const float* __restrict__ s1,
    const float* __restrict__ s2, const float* __restrict__ s3,
    u16* __restrict__ d0, u16* __restrict__ d1,
    u16* __restrict__ d2, u16* __restrict__ d3, int n4)
{
  int zz = blockIdx.y;
  const float* src = (zz == 0) ? s0 : (zz == 1) ? s1 : (zz == 2) ? s2 : s3;
  u16* dst = (zz == 0) ? d0 : (zz == 1) ? d1 : (zz == 2) ? d2 : d3;
  int i = blockIdx.x * 256 + threadIdx.x;
  if (i < n4) {
    float4 v = reinterpret_cast<const float4*>(src)[i];
    ushort4 p;
    p.x = f2b(v.x); p.y = f2b(v.y); p.z = f2b(v.z); p.w = f2b(v.w);
    reinterpret_cast<ushort4*>(dst)[i] = p;
  }
}

// ---------------------------------------------------------------------------
// Fused QKV projection: X fp32 staged w/ in-register cvt; W pre-cvt bf16.
// grid=(M/128, H).  BM=128, BN=64 (one head) x 3 outputs, BK=64.
// Epilogue: lane-parallel RMS + in-lane RoPE; V register-scatter to Vt.
// ---------------------------------------------------------------------------
__global__ __launch_bounds__(256) void qkv_fused(
    const float* __restrict__ Xf,
    const u16* __restrict__ Wqb, const u16* __restrict__ Wkb, const u16* __restrict__ Wvb,
    const float* __restrict__ cosb, const float* __restrict__ sinb,
    u16* __restrict__ Qo, u16* __restrict__ Ko, u16* __restrict__ Vto)
{
  __shared__ __align__(16) u16 smem[128 * 64 + 3 * 64 * 64];  // As | Bs[3] (40 KB)
  u16* As = smem;
  u16* Bs0 = smem + 128 * 64;

  const int m0 = blockIdx.x * 128;
  const int hh = blockIdx.y;
  const int n0 = hh * 64;

  const int tid = threadIdx.x;
  const int w = tid >> 6;
  const int lane = tid & 63;
  const int quad = lane >> 4;
  const int c = lane & 15;

  const u16* Wz[3] = {Wqb, Wkb, Wvb};

  floatx4 acc[3][2][4];
#pragma unroll
  for (int z = 0; z < 3; z++)
#pragma unroll
    for (int i = 0; i < 2; i++)
#pragma unroll
      for (int j = 0; j < 4; j++) acc[z][i][j] = (floatx4){0.f, 0.f, 0.f, 0.f};

  const int ra = tid >> 1, ca = (tid & 1) * 4;   // A: 2 thr/row, 4 chunks each
  const int rb = tid >> 2, cb = (tid & 3) * 2;   // B: 4 thr/row, 2 chunks each

  for (int k0 = 0; k0 < 384; k0 += 64) {
    float4 af[8];
#pragma unroll
    for (int j = 0; j < 4; j++) {
      const float* p = Xf + (size_t)(m0 + ra) * C_ + k0 + (ca + j) * 8;
      af[2 * j]     = *reinterpret_cast<const float4*>(p);
      af[2 * j + 1] = *reinterpret_cast<const float4*>(p + 4);
    }
    uint4 bw[3][2];
#pragma unroll
    for (int z = 0; z < 3; z++)
#pragma unroll
      for (int u = 0; u < 2; u++)
        bw[z][u] = *reinterpret_cast<const uint4*>(
            Wz[z] + (size_t)(n0 + rb) * C_ + k0 + (cb + u) * 8);
    __syncthreads();
#pragma unroll
    for (int j = 0; j < 4; j++)
      *reinterpret_cast<uint4*>(As + ra * 64 + (((ca + j) ^ (ra & 7)) * 8)) =
          pack8(af[2 * j], af[2 * j + 1]);
#pragma unroll
    for (int z = 0; z < 3; z++)
#pragma unroll
      for (int u = 0; u < 2; u++)
        *reinterpret_cast<uint4*>(Bs0 + z * 4096 + rb * 64 + (((cb + u) ^ (rb & 7)) * 8)) = bw[z][u];
    __syncthreads();

#pragma unroll
    for (int ks = 0; ks < 2; ks++) {
      short8 af2[2];
#pragma unroll
      for (int mi = 0; mi < 2; mi++) {
        int row = w * 32 + mi * 16 + c;
        af2[mi] = *reinterpret_cast<const short8*>(
            As + row * 64 + (((ks * 4 + quad) ^ (row & 7)) * 8));
      }
#pragma unroll
      for (int z = 0; z < 3; z++) {
#pragma unroll
        for (int ni = 0; ni < 4; ni++) {
          int row = ni * 16 + c;
          short8 bf = *reinterpret_cast<const short8*>(
              Bs0 + z * 4096 + row * 64 + (((ks * 4 + quad) ^ (row & 7)) * 8));
#pragma unroll
          for (int mi = 0; mi < 2; mi++)
            acc[z][mi][ni] = __builtin_amdgcn_mfma_f32_16x16x32_bf16(af2[mi], bf, acc[z][mi][ni], 0, 0, 0);
        }
      }
    }
  }

  const int bb2 = m0 >> 11;
  const int tbase = m0 & (T_ - 1);

  // ---- V: register scatter to Vt[B][H][D][T] ----
  {
    const size_t vbase = ((size_t)(bb2 * H_ + hh)) * D_ * T_;
#pragma unroll
    for (int mi = 0; mi < 2; mi++) {
      int t = tbase + w * 32 + mi * 16 + quad * 4;
#pragma unroll
      for (int ni = 0; ni < 4; ni++) {
        int d = ni * 16 + c;
        ushort4 pk;
        pk.x = f2b(acc[2][mi][ni][0]); pk.y = f2b(acc[2][mi][ni][1]);
        pk.z = f2b(acc[2][mi][ni][2]); pk.w = f2b(acc[2][mi][ni][3]);
        *reinterpret_cast<ushort4*>(Vto + vbase + (size_t)d * T_ + t) = pk;
      }
    }
  }

  // ---- Q then K: lane-parallel RMS + RoPE, LDS transpose store ----
  u16* Ep = smem;
#pragma unroll
  for (int zz = 0; zz < 2; zz++) {
    __syncthreads();
#pragma unroll
    for (int mi = 0; mi < 2; mi++) {
      float ssr[4];
#pragma unroll
      for (int r = 0; r < 4; r++) {
        float s0 = acc[zz][mi][0][r], s1 = acc[zz][mi][1][r];
        float s2 = acc[zz][mi][2][r], s3 = acc[zz][mi][3][r];
        ssr[r] = s0 * s0 + s1 * s1 + s2 * s2 + s3 * s3;
      }
#pragma unroll
      for (int off = 1; off < 16; off <<= 1)
#pragma unroll
        for (int r = 0; r < 4; r++) ssr[r] += __shfl_xor(ssr[r], off, 64);
      int rowb = w * 32 + mi * 16 + quad * 4;
#pragma unroll
      for (int r = 0; r < 4; r++) {
        float scale = rsqrtf(ssr[r] * (1.0f / 64.0f) + 1e-5f);
        int t = tbase + rowb + r;
#pragma unroll
        for (int h2 = 0; h2 < 2; h2++) {
          float cs = cosb[t * 32 + h2 * 16 + c];
          float sn = sinb[t * 32 + h2 * 16 + c];
          float x1 = acc[zz][mi][h2][r];
          float x2 = acc[zz][mi][h2 + 2][r];
          Ep[(rowb + r) * 72 + h2 * 16 + c]       = f2b((x1 * cs + x2 * sn) * scale);
          Ep[(rowb + r) * 72 + (h2 + 2) * 16 + c] = f2b((x2 * cs - x1 * sn) * scale);
        }
      }
    }
    __syncthreads();
    {
      int row = tid >> 1, half = tid & 1;
      int t = tbase + row;
      u16* Og = (zz == 0) ? Qo : Ko;
      u16* dst = Og + (((size_t)(bb2 * H_ + hh)) * T_ + t) * D_ + half * 32;
#pragma unroll
      for (int i = 0; i < 4; i++)
        *reinterpret_cast<uint4*>(dst + i * 8) =
            *reinterpret_cast<const uint4*>(Ep + row * 72 + half * 32 + i * 8);
    }
  }
}

// ---------------------------------------------------------------------------
// MFMA flash attention, fixed-max softmax.  128-THREAD blocks (2 waves),
// 64 q-rows/block, 2 q-subtiles per wave -> K/V fragments read once per
// iter serve 32 q.  Q fragments loaded directly from global (no Q LDS tile).
// Grid stays 1536 blocks (6/CU, all co-resident: LDS 16 KB).
// ---------------------------------------------------------------------------
#define EXP2_SC 0.1803368801111244f    // 0.125 * log2(e)
#define EXP2_BI (-11.541560327111404f) // -8 * log2(e)

__global__ __launch_bounds__(128) void attn_mfma(
    const u16* __restrict__ Qg, const u16* __restrict__ Kg,
    const u16* __restrict__ Vtg, u16* __restrict__ Yg)
{
  __shared__ __align__(16) u16 smem[8192];   // Ks[0,4096) Vs[4096,8192)
  u16* Ks = smem;
  u16* Vs = smem + 4096;

  const int tid = threadIdx.x;    // 0..127
  const int w = tid >> 6;         // 0..1
  const int lane = tid & 63;
  const int quad = lane >> 4;
  const int c = lane & 15;

  const int bh = blockIdx.y;
  const int q0 = blockIdx.x * 64;
  const size_t baseQK = (size_t)bh * T_ * D_;
  const size_t baseV  = (size_t)bh * D_ * T_;

  // Q fragments direct from global: wave w, subtile qs -> rows (w*2+qs)*16+c
  short8 qf[2][2];
#pragma unroll
  for (int qs = 0; qs < 2; qs++) {
    const u16* qp = Qg + baseQK + (size_t)(q0 + (w * 2 + qs) * 16 + c) * D_ + quad * 8;
    qf[qs][0] = *reinterpret_cast<const short8*>(qp);
    qf[qs][1] = *reinterpret_cast<const short8*>(qp + 32);
  }

  floatx4 o_acc[2][4];
#pragma unroll
  for (int qs = 0; qs < 2; qs++)
#pragma unroll
    for (int i = 0; i < 4; i++) o_acc[qs][i] = (floatx4){0.f, 0.f, 0.f, 0.f};
  float l_part[2] = {0.f, 0.f};

  const int slA = (((quad & 1) * 2) << 4) | c;
  const int slB = slA + 16;
  const bool hiTile = (quad >> 1) != 0;

  const int sr = tid >> 1, sh4 = (tid & 1) * 4;   // staging: row, base chunk

  for (int kt = 0; kt < T_; kt += 64) {
    uint4 ka[4], va[4];
    {
      const u16* s  = Kg + baseQK + (size_t)(kt + sr) * D_;
      const u16* sv = Vtg + baseV + (size_t)sr * T_ + kt;
#pragma unroll
      for (int j = 0; j < 4; j++) {
        ka[j] = *reinterpret_cast<const uint4*>(s + (sh4 + j) * 8);
        va[j] = *reinterpret_cast<const uint4*>(sv + (sh4 + j) * 8);
      }
    }
    __syncthreads();
#pragma unroll
    for (int j = 0; j < 4; j++) {
      *reinterpret_cast<uint4*>(Ks + sr * 64 + (((sh4 + j) ^ (sr & 7)) * 8)) = ka[j];
      *reinterpret_cast<uint4*>(Vs + sr * 64 + (((sh4 + j) ^ (sr & 7)) * 8)) = va[j];
    }
    __syncthreads();

    // S^T = K · Q^T for both q-subtiles; K frags read once
    floatx4 st[2][4];
#pragma unroll
    for (int qs = 0; qs < 2; qs++)
#pragma unroll
      for (int i = 0; i < 4; i++) st[qs][i] = (floatx4){0.f, 0.f, 0.f, 0.f};
#pragma unroll
    for (int mt = 0; mt < 4; mt++) {
      int krow = mt * 16 + c;
      short8 kf0 = *reinterpret_cast<const short8*>(
          Ks + krow * 64 + (((0 + quad) ^ (krow & 7)) * 8));
      short8 kf1 = *reinterpret_cast<const short8*>(
          Ks + krow * 64 + (((4 + quad) ^ (krow & 7)) * 8));
#pragma unroll
      for (int qs = 0; qs < 2; qs++) {
        st[qs][mt] = __builtin_amdgcn_mfma_f32_16x16x32_bf16(kf0, qf[qs][0], st[qs][mt], 0, 0, 0);
        st[qs][mt] = __builtin_amdgcn_mfma_f32_16x16x32_bf16(kf1, qf[qs][1], st[qs][mt], 0, 0, 0);
      }
    }

    // fixed-max softmax (p = exp2(s*sc + bi)) + bf16 pair packing
    u32 pk[2][2][4];
#pragma unroll
    for (int qs = 0; qs < 2; qs++) {
      float p[4][4];
#pragma unroll
      for (int mt = 0; mt < 4; mt++)
#pragma unroll
        for (int r = 0; r < 4; r++) {
          float pv = exp2f(fmaf(st[qs][mt][r], EXP2_SC, EXP2_BI));
          p[mt][r] = pv;
          l_part[qs] += pv;
        }
#pragma unroll
      for (int s2 = 0; s2 < 2; s2++)
#pragma unroll
        for (int r = 0; r < 4; r++)
          pk[qs][s2][r] = pack_bf16(p[2 * s2][r], p[2 * s2 + 1][r]);
    }

    // O^T += V^T · P^T ; V frags read once, shared across subtiles
#pragma unroll
    for (int s2 = 0; s2 < 2; s2++) {
      short8 bf[2];
#pragma unroll
      for (int qs = 0; qs < 2; qs++) {
        u32 wa[4], wb[4];
#pragma unroll
        for (int r = 0; r < 4; r++) {
          wa[r] = (u32)__shfl((int)pk[qs][s2][r], slA, 64);
          wb[r] = (u32)__shfl((int)pk[qs][s2][r], slB, 64);
        }
        u32 bfr[4];
        if (hiTile) {
          bfr[0] = (wa[0] >> 16) | (wa[1] & 0xffff0000u);
          bfr[1] = (wa[2] >> 16) | (wa[3] & 0xffff0000u);
          bfr[2] = (wb[0] >> 16) | (wb[1] & 0xffff0000u);
          bfr[3] = (wb[2] >> 16) | (wb[3] & 0xffff0000u);
        } else {
          bfr[0] = (wa[0] & 0xffffu) | (wa[1] << 16);
          bfr[1] = (wa[2] & 0xffffu) | (wa[3] << 16);
          bfr[2] = (wb[0] & 0xffffu) | (wb[1] << 16);
          bfr[3] = (wb[2] & 0xffffu) | (wb[3] << 16);
        }
        u32* bfu = reinterpret_cast<u32*>(&bf[qs]);
        bfu[0] = bfr[0]; bfu[1] = bfr[1]; bfu[2] = bfr[2]; bfu[3] = bfr[3];
      }
#pragma unroll
      for (int mt = 0; mt < 4; mt++) {
        int vrow = mt * 16 + c;
        short8 vf = *reinterpret_cast<const short8*>(
            Vs + vrow * 64 + (((4 * s2 + quad) ^ (vrow & 7)) * 8));
#pragma unroll
        for (int qs = 0; qs < 2; qs++)
          o_acc[qs][mt] = __builtin_amdgcn_mfma_f32_16x16x32_bf16(vf, bf[qs], o_acc[qs][mt], 0, 0, 0);
      }
    }
  }

  float inv[2];
#pragma unroll
  for (int qs = 0; qs < 2; qs++) {
    float l = l_part[qs];
    l += __shfl_xor(l, 16, 64);
    l += __shfl_xor(l, 32, 64);
    inv[qs] = 1.0f / l;
  }

  // epilogue: LDS transpose (aliases Ks/Vs), coalesced store
  __syncthreads();
  u16* Ot = smem + w * 2304;              // per wave: 2 subtiles x 16q x 72
#pragma unroll
  for (int qs = 0; qs < 2; qs++)
#pragma unroll
    for (int mt = 0; mt < 4; mt++) {
      ushort4 pko;
      pko.x = f2b(o_acc[qs][mt][0] * inv[qs]);
      pko.y = f2b(o_acc[qs][mt][1] * inv[qs]);
      pko.z = f2b(o_acc[qs][mt][2] * inv[qs]);
      pko.w = f2b(o_acc[qs][mt][3] * inv[qs]);
      *reinterpret_cast<ushort4*>(Ot + qs * 1152 + c * 72 + mt * 16 + quad * 4) = pko;
    }
  __syncthreads();
  {
    int row = tid >> 1, half = tid & 1;   // q-row 0..63, d-half
    const u16* src = smem + (row >> 5) * 2304 + ((row >> 4) & 1) * 1152 + (row & 15) * 72 + half * 32;
    int t = q0 + row;
    int b = bh / H_, h = bh % H_;
    u16* dst = Yg + ((size_t)b * T_ + t) * C_ + h * 64 + half * 32;
#pragma unroll
    for (int i = 0; i < 4; i++)
      *reinterpret_cast<uint4*>(dst + i * 8) =
          *reinterpret_cast<const uint4*>(src + i * 8);
  }
}

// ---------------------------------------------------------------------------
// Out projection: Y bf16 x Wo bf16 (pre-cvt) -> fp32, LDS-transpose epilogue.
// ---------------------------------------------------------------------------
__global__ __launch_bounds__(256) void out_mfma(
    const u16* __restrict__ Xb, const u16* __restrict__ Wb, float* __restrict__ Og)
{
  __shared__ __align__(16) u16 smem[17408];   // As|Bs, then fp32 Ep (34816 B)
  u16* As = smem;
  u16* Bs = smem + 128 * 64;

  const int m0 = blockIdx.x * 128;
  const int n0 = blockIdx.y * 64;

  const int tid = threadIdx.x;
  const int w = tid >> 6;
  const int lane = tid & 63;
  const int quad = lane >> 4;
  const int c = lane & 15;

  floatx4 acc[2][4];
#pragma unroll
  for (int i = 0; i < 2; i++)
#pragma unroll
    for (int j = 0; j < 4; j++) acc[i][j] = (floatx4){0.f, 0.f, 0.f, 0.f};

  const int ra = tid >> 1, ca = (tid & 1) * 4;
  const int rb = tid >> 2, cb = (tid & 3) * 2;

  for (int k0 = 0; k0 < 384; k0 += 64) {
    uint4 a[4], b[2];
#pragma unroll
    for (int j = 0; j < 4; j++)
      a[j] = *reinterpret_cast<const uint4*>(Xb + (size_t)(m0 + ra) * C_ + k0 + (ca + j) * 8);
#pragma unroll
    for (int u = 0; u < 2; u++)
      b[u] = *reinterpret_cast<const uint4*>(Wb + (size_t)(n0 + rb) * C_ + k0 + (cb + u) * 8);
    __syncthreads();
#pragma unroll
    for (int j = 0; j < 4; j++)
      *reinterpret_cast<uint4*>(As + ra * 64 + (((ca + j) ^ (ra & 7)) * 8)) = a[j];
#pragma unroll
    for (int u = 0; u < 2; u++)
      *reinterpret_cast<uint4*>(Bs + rb * 64 + (((cb + u) ^ (rb & 7)) * 8)) = b[u];
    __syncthreads();

#pragma unroll
    for (int ks = 0; ks < 2; ks++) {
      short8 af[2], bf[4];
#pragma unroll
      for (int mi = 0; mi < 2; mi++) {
        int row = w * 32 + mi * 16 + c;
        af[mi] = *reinterpret_cast<const short8*>(
            As + row * 64 + (((ks * 4 + quad) ^ (row & 7)) * 8));
      }
#pragma unroll
      for (int ni = 0; ni < 4; ni++) {
        int row = ni * 16 + c;
        bf[ni] = *reinterpret_cast<const short8*>(
            Bs + row * 64 + (((ks * 4 + quad) ^ (row & 7)) * 8));
      }
#pragma unroll
      for (int mi = 0; mi < 2; mi++)
#pragma unroll
        for (int ni = 0; ni < 4; ni++)
          acc[mi][ni] = __builtin_amdgcn_mfma_f32_16x16x32_bf16(af[mi], bf[ni], acc[mi][ni], 0, 0, 0);
    }
  }

  __syncthreads();
  float* Ep = reinterpret_cast<float*>(smem) + w * (32 * 68);
#pragma unroll
  for (int mi = 0; mi < 2; mi++)
#pragma unroll
    for (int ni = 0; ni < 4; ni++) {
      int rw = mi * 16 + quad * 4;
      int col = ni * 16 + c;
#pragma unroll
      for (int r = 0; r < 4; r++)
        Ep[(rw + r) * 68 + col] = acc[mi][ni][r];
    }
  __syncthreads();
  {
    int rw2 = lane >> 1, half = lane & 1;
    const float* src = Ep + rw2 * 68 + half * 32;
    float* dst = Og + (size_t)(m0 + w * 32 + rw2) * C_ + n0 + half * 32;
#pragma unroll
    for (int i = 0; i < 8; i++)
      *reinterpret_cast<float4*>(dst + i * 4) =
          *reinterpret_cast<const float4*>(src + i * 4);
  }
}

// ---------------------------------------------------------------------------
extern "C" void kernel_launch(void* const* d_in, const int* in_sizes, int n_in,
                              void* d_out, int out_size, void* d_ws, size_t ws_size,
                              hipStream_t stream) {
  (void)in_sizes; (void)n_in; (void)out_size; (void)ws_size;
  const float* x    = (const float*)d_in[0];
  const float* Wq   = (const float*)d_in[1];
  const float* Wk   = (const float*)d_in[2];
  const float* Wv   = (const float*)d_in[3];
  const float* Wo   = (const float*)d_in[4];
  const float* cosb = (const float*)d_in[5];
  const float* sinb = (const float*)d_in[6];

  const size_t MC = (size_t)M_ * C_;    // 6291456
  const size_t WN = (size_t)C_ * C_;    // 147456
  u16* ws = (u16*)d_ws;
  u16* Wqb = ws;
  u16* Wkb = Wqb + WN;
  u16* Wvb = Wkb + WN;
  u16* Wob = Wvb + WN;
  u16* Q   = Wob + WN;                  // [B][H][T][D] bf16
  u16* K   = Q + MC;
  u16* Vt  = K + MC;                    // [B][H][D][T] bf16
  u16* Y   = Vt + MC;                   // [B*T][C] bf16
  float* out = (float*)d_out;

  cvt_w4<<<dim3((int)(WN / 4 / 256), 4), 256, 0, stream>>>(
      Wq, Wk, Wv, Wo, Wqb, Wkb, Wvb, Wob, (int)(WN / 4));

  qkv_fused<<<dim3(M_ / 128, H_), 256, 0, stream>>>(
      x, Wqb, Wkb, Wvb, cosb, sinb, Q, K, Vt);

  attn_mfma<<<dim3(T_ / 64, B_ * H_), 128, 0, stream>>>(Q, K, Vt, Y);

  out_mfma<<<dim3(M_ / 128, H_), 256, 0, stream>>>(Y, Wob, out);
}

// Round 11
// 285.880 us; speedup vs baseline: 1.5556x; 1.5556x over previous
//
#include <hip/hip_runtime.h>
#include <hip/hip_bf16.h>
#include <stdint.h>

#define B_ 8
#define T_ 2048
#define C_ 384
#define H_ 6
#define D_ 64
#define M_ (B_*T_)   // 16384

typedef unsigned short u16;
typedef unsigned int u32;
typedef __attribute__((ext_vector_type(8))) short short8;
typedef __attribute__((ext_vector_type(4))) float floatx4;

__device__ __forceinline__ float b2f(u16 v) {
  union { unsigned u; float f; } x; x.u = ((unsigned)v) << 16; return x.f;
}
__device__ __forceinline__ u16 f2b(float f) {
  union { float f; unsigned u; } x; x.f = f;
  unsigned r = x.u + 0x7fffu + ((x.u >> 16) & 1u);  // round-nearest-even
  return (u16)(r >> 16);
}
__device__ __forceinline__ u32 pack_bf16(float a, float b) {
  union { __hip_bfloat162 h; u32 u; } x;
  x.h = __float22bfloat162_rn(float2{a, b});
  return x.u;
}
__device__ __forceinline__ uint4 pack8(const float4& lo, const float4& hi) {
  uint4 r;
  r.x = pack_bf16(lo.x, lo.y); r.y = pack_bf16(lo.z, lo.w);
  r.z = pack_bf16(hi.x, hi.y); r.w = pack_bf16(hi.z, hi.w);
  return r;
}

// ---------------------------------------------------------------------------
// Fused QKV projection (round-9 config: fp32 X and W staged w/ in-reg cvt).
// grid=(M/128, H).  BM=128, BN=64 (one head) x 3 outputs, BK=64.
// Epilogue: lane-parallel RMS + in-lane RoPE; V register-scatter to Vt.
// ---------------------------------------------------------------------------
__global__ __launch_bounds__(256) void qkv_fused(
    const float* __restrict__ Xf,
    const float* __restrict__ Wqf, const float* __restrict__ Wkf, const float* __restrict__ Wvf,
    const float* __restrict__ cosb, const float* __restrict__ sinb,
    u16* __restrict__ Qo, u16* __restrict__ Ko, u16* __restrict__ Vto)
{
  __shared__ __align__(16) u16 smem[128 * 64 + 3 * 64 * 64];  // As | Bs[3] (40 KB)
  u16* As = smem;
  u16* Bs0 = smem + 128 * 64;

  const int m0 = blockIdx.x * 128;
  const int hh = blockIdx.y;
  const int n0 = hh * 64;

  const int tid = threadIdx.x;
  const int w = tid >> 6;
  const int lane = tid & 63;
  const int quad = lane >> 4;
  const int c = lane & 15;

  const float* Wz[3] = {Wqf, Wkf, Wvf};

  floatx4 acc[3][2][4];
#pragma unroll
  for (int z = 0; z < 3; z++)
#pragma unroll
    for (int i = 0; i < 2; i++)
#pragma unroll
      for (int j = 0; j < 4; j++) acc[z][i][j] = (floatx4){0.f, 0.f, 0.f, 0.f};

  const int ra = tid >> 1, ca = (tid & 1) * 4;   // A: 2 thr/row, 4 chunks each
  const int rb = tid >> 2, cb = (tid & 3) * 2;   // B: 4 thr/row, 2 chunks each

  for (int k0 = 0; k0 < 384; k0 += 64) {
    float4 af[8];
#pragma unroll
    for (int j = 0; j < 4; j++) {
      const float* p = Xf + (size_t)(m0 + ra) * C_ + k0 + (ca + j) * 8;
      af[2 * j]     = *reinterpret_cast<const float4*>(p);
      af[2 * j + 1] = *reinterpret_cast<const float4*>(p + 4);
    }
    float4 bw[3][4];
#pragma unroll
    for (int z = 0; z < 3; z++)
#pragma unroll
      for (int u = 0; u < 2; u++) {
        const float* p = Wz[z] + (size_t)(n0 + rb) * C_ + k0 + (cb + u) * 8;
        bw[z][2 * u]     = *reinterpret_cast<const float4*>(p);
        bw[z][2 * u + 1] = *reinterpret_cast<const float4*>(p + 4);
      }
    __syncthreads();
#pragma unroll
    for (int j = 0; j < 4; j++)
      *reinterpret_cast<uint4*>(As + ra * 64 + (((ca + j) ^ (ra & 7)) * 8)) =
          pack8(af[2 * j], af[2 * j + 1]);
#pragma unroll
    for (int z = 0; z < 3; z++)
#pragma unroll
      for (int u = 0; u < 2; u++)
        *reinterpret_cast<uint4*>(Bs0 + z * 4096 + rb * 64 + (((cb + u) ^ (rb & 7)) * 8)) =
            pack8(bw[z][2 * u], bw[z][2 * u + 1]);
    __syncthreads();

#pragma unroll
    for (int ks = 0; ks < 2; ks++) {
      short8 af2[2];
#pragma unroll
      for (int mi = 0; mi < 2; mi++) {
        int row = w * 32 + mi * 16 + c;
        af2[mi] = *reinterpret_cast<const short8*>(
            As + row * 64 + (((ks * 4 + quad) ^ (row & 7)) * 8));
      }
#pragma unroll
      for (int z = 0; z < 3; z++) {
#pragma unroll
        for (int ni = 0; ni < 4; ni++) {
          int row = ni * 16 + c;
          short8 bf = *reinterpret_cast<const short8*>(
              Bs0 + z * 4096 + row * 64 + (((ks * 4 + quad) ^ (row & 7)) * 8));
#pragma unroll
          for (int mi = 0; mi < 2; mi++)
            acc[z][mi][ni] = __builtin_amdgcn_mfma_f32_16x16x32_bf16(af2[mi], bf, acc[z][mi][ni], 0, 0, 0);
        }
      }
    }
  }

  const int bb2 = m0 >> 11;
  const int tbase = m0 & (T_ - 1);

  // ---- V: register scatter to Vt[B][H][D][T] ----
  {
    const size_t vbase = ((size_t)(bb2 * H_ + hh)) * D_ * T_;
#pragma unroll
    for (int mi = 0; mi < 2; mi++) {
      int t = tbase + w * 32 + mi * 16 + quad * 4;
#pragma unroll
      for (int ni = 0; ni < 4; ni++) {
        int d = ni * 16 + c;
        ushort4 pk;
        pk.x = f2b(acc[2][mi][ni][0]); pk.y = f2b(acc[2][mi][ni][1]);
        pk.z = f2b(acc[2][mi][ni][2]); pk.w = f2b(acc[2][mi][ni][3]);
        *reinterpret_cast<ushort4*>(Vto + vbase + (size_t)d * T_ + t) = pk;
      }
    }
  }

  // ---- Q then K: lane-parallel RMS + RoPE, LDS transpose store ----
  u16* Ep = smem;
#pragma unroll
  for (int zz = 0; zz < 2; zz++) {
    __syncthreads();
#pragma unroll
    for (int mi = 0; mi < 2; mi++) {
      float ssr[4];
#pragma unroll
      for (int r = 0; r < 4; r++) {
        float s0 = acc[zz][mi][0][r], s1 = acc[zz][mi][1][r];
        float s2 = acc[zz][mi][2][r], s3 = acc[zz][mi][3][r];
        ssr[r] = s0 * s0 + s1 * s1 + s2 * s2 + s3 * s3;
      }
#pragma unroll
      for (int off = 1; off < 16; off <<= 1)
#pragma unroll
        for (int r = 0; r < 4; r++) ssr[r] += __shfl_xor(ssr[r], off, 64);
      int rowb = w * 32 + mi * 16 + quad * 4;
#pragma unroll
      for (int r = 0; r < 4; r++) {
        float scale = rsqrtf(ssr[r] * (1.0f / 64.0f) + 1e-5f);
        int t = tbase + rowb + r;
#pragma unroll
        for (int h2 = 0; h2 < 2; h2++) {
          float cs = cosb[t * 32 + h2 * 16 + c];
          float sn = sinb[t * 32 + h2 * 16 + c];
          float x1 = acc[zz][mi][h2][r];
          float x2 = acc[zz][mi][h2 + 2][r];
          Ep[(rowb + r) * 72 + h2 * 16 + c]       = f2b((x1 * cs + x2 * sn) * scale);
          Ep[(rowb + r) * 72 + (h2 + 2) * 16 + c] = f2b((x2 * cs - x1 * sn) * scale);
        }
      }
    }
    __syncthreads();
    {
      int row = tid >> 1, half = tid & 1;
      int t = tbase + row;
      u16* Og = (zz == 0) ? Qo : Ko;
      u16* dst = Og + (((size_t)(bb2 * H_ + hh)) * T_ + t) * D_ + half * 32;
#pragma unroll
      for (int i = 0; i < 4; i++)
        *reinterpret_cast<uint4*>(dst + i * 8) =
            *reinterpret_cast<const uint4*>(Ep + row * 72 + half * 32 + i * 8);
    }
  }
}

// ---------------------------------------------------------------------------
// MFMA flash attention — round-8 proven shape (256 thr, 64 q-rows, Qs LDS
// tile, 40 VGPR, no spill), fixed-max softmax via exp2f (folded constants).
// ---------------------------------------------------------------------------
#define EXP2_SC 0.1803368801111244f    // 0.125 * log2(e)
#define EXP2_BI (-11.541560327111404f) // -8 * log2(e)

__global__ __launch_bounds__(256) void attn_mfma(
    const u16* __restrict__ Qg, const u16* __restrict__ Kg,
    const u16* __restrict__ Vtg, u16* __restrict__ Yg)
{
  __shared__ __align__(16) u16 smem[12288];   // Qs | Ks | Vs
  u16* Qs = smem;
  u16* Ks = smem + 4096;
  u16* Vs = smem + 8192;

  const int tid = threadIdx.x;
  const int w = tid >> 6;
  const int lane = tid & 63;
  const int quad = lane >> 4;
  const int c = lane & 15;

  const int bh = blockIdx.y;
  const int q0 = blockIdx.x * 64;
  const size_t baseQK = (size_t)bh * T_ * D_;
  const size_t baseV  = (size_t)bh * D_ * T_;

  {
    int r = tid >> 2, ch = tid & 3;
    const u16* s = Qg + baseQK + (size_t)(q0 + r) * D_ + ch * 8;
    uint4 a = *reinterpret_cast<const uint4*>(s);
    uint4 b = *reinterpret_cast<const uint4*>(s + 32);
    *reinterpret_cast<uint4*>(Qs + r * 64 + ((ch ^ (r & 7)) * 8)) = a;
    *reinterpret_cast<uint4*>(Qs + r * 64 + (((ch + 4) ^ (r & 7)) * 8)) = b;
  }
  __syncthreads();

  const int qrow = w * 16 + c;
  short8 qf0 = *reinterpret_cast<const short8*>(
      Qs + qrow * 64 + (((0 + quad) ^ (qrow & 7)) * 8));
  short8 qf1 = *reinterpret_cast<const short8*>(
      Qs + qrow * 64 + (((4 + quad) ^ (qrow & 7)) * 8));

  floatx4 o_acc[4];
#pragma unroll
  for (int i = 0; i < 4; i++) o_acc[i] = (floatx4){0.f, 0.f, 0.f, 0.f};
  float l_part = 0.0f;

  const int slA = (((quad & 1) * 2) << 4) | c;
  const int slB = slA + 16;
  const bool hiTile = (quad >> 1) != 0;

  for (int kt = 0; kt < T_; kt += 64) {
    __syncthreads();
    {
      int r = tid >> 2, ch = tid & 3;
      const u16* s = Kg + baseQK + (size_t)(kt + r) * D_ + ch * 8;
      uint4 a = *reinterpret_cast<const uint4*>(s);
      uint4 b = *reinterpret_cast<const uint4*>(s + 32);
      *reinterpret_cast<uint4*>(Ks + r * 64 + ((ch ^ (r & 7)) * 8)) = a;
      *reinterpret_cast<uint4*>(Ks + r * 64 + (((ch + 4) ^ (r & 7)) * 8)) = b;
      const u16* sv = Vtg + baseV + (size_t)r * T_ + kt + ch * 8;
      uint4 va = *reinterpret_cast<const uint4*>(sv);
      uint4 vb = *reinterpret_cast<const uint4*>(sv + 32);
      *reinterpret_cast<uint4*>(Vs + r * 64 + ((ch ^ (r & 7)) * 8)) = va;
      *reinterpret_cast<uint4*>(Vs + r * 64 + (((ch + 4) ^ (r & 7)) * 8)) = vb;
    }
    __syncthreads();

    floatx4 st[4];
#pragma unroll
    for (int i = 0; i < 4; i++) st[i] = (floatx4){0.f, 0.f, 0.f, 0.f};
#pragma unroll
    for (int mt = 0; mt < 4; mt++) {
      int krow = mt * 16 + c;
      short8 kf0 = *reinterpret_cast<const short8*>(
          Ks + krow * 64 + (((0 + quad) ^ (krow & 7)) * 8));
      st[mt] = __builtin_amdgcn_mfma_f32_16x16x32_bf16(kf0, qf0, st[mt], 0, 0, 0);
      short8 kf1 = *reinterpret_cast<const short8*>(
          Ks + krow * 64 + (((4 + quad) ^ (krow & 7)) * 8));
      st[mt] = __builtin_amdgcn_mfma_f32_16x16x32_bf16(kf1, qf1, st[mt], 0, 0, 0);
    }

    // fixed-max softmax: p = exp2(s*0.125*log2e - 8*log2e)
    float p[4][4];
#pragma unroll
    for (int mt = 0; mt < 4; mt++)
#pragma unroll
      for (int r = 0; r < 4; r++) {
        float pv = exp2f(fmaf(st[mt][r], EXP2_SC, EXP2_BI));
        p[mt][r] = pv;
        l_part += pv;
      }

#pragma unroll
    for (int s2 = 0; s2 < 2; s2++) {
      u32 pk[4];
#pragma unroll
      for (int r = 0; r < 4; r++)
        pk[r] = pack_bf16(p[2 * s2][r], p[2 * s2 + 1][r]);
      u32 wa[4], wb[4];
#pragma unroll
      for (int r = 0; r < 4; r++) {
        wa[r] = (u32)__shfl((int)pk[r], slA, 64);
        wb[r] = (u32)__shfl((int)pk[r], slB, 64);
      }
      u32 bfr[4];
      if (hiTile) {
        bfr[0] = (wa[0] >> 16) | (wa[1] & 0xffff0000u);
        bfr[1] = (wa[2] >> 16) | (wa[3] & 0xffff0000u);
        bfr[2] = (wb[0] >> 16) | (wb[1] & 0xffff0000u);
        bfr[3] = (wb[2] >> 16) | (wb[3] & 0xffff0000u);
      } else {
        bfr[0] = (wa[0] & 0xffffu) | (wa[1] << 16);
        bfr[1] = (wa[2] & 0xffffu) | (wa[3] << 16);
        bfr[2] = (wb[0] & 0xffffu) | (wb[1] << 16);
        bfr[3] = (wb[2] & 0xffffu) | (wb[3] << 16);
      }
      short8 bf;
      u32* bfu = reinterpret_cast<u32*>(&bf);
      bfu[0] = bfr[0]; bfu[1] = bfr[1]; bfu[2] = bfr[2]; bfu[3] = bfr[3];
#pragma unroll
      for (int mt = 0; mt < 4; mt++) {
        int vrow = mt * 16 + c;
        short8 vf = *reinterpret_cast<const short8*>(
            Vs + vrow * 64 + (((4 * s2 + quad) ^ (vrow & 7)) * 8));
        o_acc[mt] = __builtin_amdgcn_mfma_f32_16x16x32_bf16(vf, bf, o_acc[mt], 0, 0, 0);
      }
    }
  }

  float l_run = l_part;
  l_run += __shfl_xor(l_run, 16, 64);
  l_run += __shfl_xor(l_run, 32, 64);

  __syncthreads();
  u16* Ot = smem + 4096 + w * 1152;
  float inv = 1.0f / l_run;
#pragma unroll
  for (int mt = 0; mt < 4; mt++) {
    ushort4 pk;
    pk.x = f2b(o_acc[mt][0] * inv);
    pk.y = f2b(o_acc[mt][1] * inv);
    pk.z = f2b(o_acc[mt][2] * inv);
    pk.w = f2b(o_acc[mt][3] * inv);
    *reinterpret_cast<ushort4*>(Ot + c * 72 + mt * 16 + quad * 4) = pk;
  }
  __syncthreads();
  {
    int rq = lane >> 2, dc = (lane & 3) * 16;
    uint4 r0 = *reinterpret_cast<const uint4*>(Ot + rq * 72 + dc);
    uint4 r1 = *reinterpret_cast<const uint4*>(Ot + rq * 72 + dc + 8);
    int t = q0 + w * 16 + rq;
    int b = bh / H_, h = bh % H_;
    size_t yi = ((size_t)b * T_ + t) * C_ + h * 64 + dc;
    *reinterpret_cast<uint4*>(Yg + yi) = r0;
    *reinterpret_cast<uint4*>(Yg + yi + 8) = r1;
  }
}

// ---------------------------------------------------------------------------
// Out projection (round-9 config): Y bf16 x Wo fp32 (staged w/ in-reg cvt)
// -> fp32, LDS-transpose epilogue for coalesced float4 stores.
// ---------------------------------------------------------------------------
__global__ __launch_bounds__(256) void out_mfma(
    const u16* __restrict__ Xb, const float* __restrict__ Wf, float* __restrict__ Og)
{
  __shared__ __align__(16) u16 smem[17408];   // As|Bs, then fp32 Ep (34816 B)
  u16* As = smem;
  u16* Bs = smem + 128 * 64;

  const int m0 = blockIdx.x * 128;
  const int n0 = blockIdx.y * 64;

  const int tid = threadIdx.x;
  const int w = tid >> 6;
  const int lane = tid & 63;
  const int quad = lane >> 4;
  const int c = lane & 15;

  floatx4 acc[2][4];
#pragma unroll
  for (int i = 0; i < 2; i++)
#pragma unroll
    for (int j = 0; j < 4; j++) acc[i][j] = (floatx4){0.f, 0.f, 0.f, 0.f};

  const int ra = tid >> 1, ca = (tid & 1) * 4;
  const int rb = tid >> 2, cb = (tid & 3) * 2;

  for (int k0 = 0; k0 < 384; k0 += 64) {
    uint4 a[4];
#pragma unroll
    for (int j = 0; j < 4; j++)
      a[j] = *reinterpret_cast<const uint4*>(Xb + (size_t)(m0 + ra) * C_ + k0 + (ca + j) * 8);
    float4 bw[4];
#pragma unroll
    for (int u = 0; u < 2; u++) {
      const float* p = Wf + (size_t)(n0 + rb) * C_ + k0 + (cb + u) * 8;
      bw[2 * u]     = *reinterpret_cast<const float4*>(p);
      bw[2 * u + 1] = *reinterpret_cast<const float4*>(p + 4);
    }
    __syncthreads();
#pragma unroll
    for (int j = 0; j < 4; j++)
      *reinterpret_cast<uint4*>(As + ra * 64 + (((ca + j) ^ (ra & 7)) * 8)) = a[j];
#pragma unroll
    for (int u = 0; u < 2; u++)
      *reinterpret_cast<uint4*>(Bs + rb * 64 + (((cb + u) ^ (rb & 7)) * 8)) =
          pack8(bw[2 * u], bw[2 * u + 1]);
    __syncthreads();

#pragma unroll
    for (int ks = 0; ks < 2; ks++) {
      short8 af[2], bf[4];
#pragma unroll
      for (int mi = 0; mi < 2; mi++) {
        int row = w * 32 + mi * 16 + c;
        af[mi] = *reinterpret_cast<const short8*>(
            As + row * 64 + (((ks * 4 + quad) ^ (row & 7)) * 8));
      }
#pragma unroll
      for (int ni = 0; ni < 4; ni++) {
        int row = ni * 16 + c;
        bf[ni] = *reinterpret_cast<const short8*>(
            Bs + row * 64 + (((ks * 4 + quad) ^ (row & 7)) * 8));
      }
#pragma unroll
      for (int mi = 0; mi < 2; mi++)
#pragma unroll
        for (int ni = 0; ni < 4; ni++)
          acc[mi][ni] = __builtin_amdgcn_mfma_f32_16x16x32_bf16(af[mi], bf[ni], acc[mi][ni], 0, 0, 0);
    }
  }

  __syncthreads();
  float* Ep = reinterpret_cast<float*>(smem) + w * (32 * 68);
#pragma unroll
  for (int mi = 0; mi < 2; mi++)
#pragma unroll
    for (int ni = 0; ni < 4; ni++) {
      int rw = mi * 16 + quad * 4;
      int col = ni * 16 + c;
#pragma unroll
      for (int r = 0; r < 4; r++)
        Ep[(rw + r) * 68 + col] = acc[mi][ni][r];
    }
  __syncthreads();
  {
    int rw2 = lane >> 1, half = lane & 1;
    const float* src = Ep + rw2 * 68 + half * 32;
    float* dst = Og + (size_t)(m0 + w * 32 + rw2) * C_ + n0 + half * 32;
#pragma unroll
    for (int i = 0; i < 8; i++)
      *reinterpret_cast<float4*>(dst + i * 4) =
          *reinterpret_cast<const float4*>(src + i * 4);
  }
}

// ---------------------------------------------------------------------------
extern "C" void kernel_launch(void* const* d_in, const int* in_sizes, int n_in,
                              void* d_out, int out_size, void* d_ws, size_t ws_size,
                              hipStream_t stream) {
  (void)in_sizes; (void)n_in; (void)out_size; (void)ws_size;
  const float* x    = (const float*)d_in[0];
  const float* Wq   = (const float*)d_in[1];
  const float* Wk   = (const float*)d_in[2];
  const float* Wv   = (const float*)d_in[3];
  const float* Wo   = (const float*)d_in[4];
  const float* cosb = (const float*)d_in[5];
  const float* sinb = (const float*)d_in[6];

  const size_t MC = (size_t)M_ * C_;    // 6291456
  u16* ws = (u16*)d_ws;
  u16* Q   = ws;                        // [B][H][T][D] bf16
  u16* K   = Q + MC;
  u16* Vt  = K + MC;                    // [B][H][D][T] bf16
  u16* Y   = Vt + MC;                   // [B*T][C] bf16
  float* out = (float*)d_out;

  qkv_fused<<<dim3(M_ / 128, H_), 256, 0, stream>>>(
      x, Wq, Wk, Wv, cosb, sinb, Q, K, Vt);

  attn_mfma<<<dim3(T_ / 64, B_ * H_), 256, 0, stream>>>(Q, K, Vt, Y);

  out_mfma<<<dim3(M_ / 128, H_), 256, 0, stream>>>(Y, Wo, out);
}